// Round 1
// baseline (299.386 us; speedup 1.0000x reference)
//
#include <hip/hip_runtime.h>
#include <hip/hip_bf16.h>
#include <math.h>

// BitLinearAttention on gfx950.
// B=2, S=2048, D=1024, H=16, Hd=64, T=B*S=4096. All GEMMs done as exact-integer
// bf16 MFMA (qint in [-128,127], ternary weights), scales applied in epilogue.

typedef float  f32x4  __attribute__((ext_vector_type(4)));
typedef __bf16 bf16x8 __attribute__((ext_vector_type(8)));
typedef unsigned int u32x4 __attribute__((ext_vector_type(4)));

#define EPSV 1e-5f

__device__ __forceinline__ f32x4 mfma16(bf16x8 a, bf16x8 b, f32x4 c) {
    return __builtin_amdgcn_mfma_f32_16x16x32_bf16(a, b, c, 0, 0, 0);
}

// ---------------- weight |.| sum (fp64 accumulate) ----------------
__global__ __launch_bounds__(256) void k_wsum(const float* __restrict__ w0, const float* __restrict__ w1,
                                              const float* __restrict__ w2, const float* __restrict__ w3,
                                              double* __restrict__ wsum) {
    int w = blockIdx.x >> 6, chunk = blockIdx.x & 63, tid = threadIdx.x;
    const float* W = (w == 0) ? w0 : (w == 1) ? w1 : (w == 2) ? w2 : w3;
    const float* base = W + (size_t)chunk * 16384;
    float s = 0.f;
#pragma unroll
    for (int i = 0; i < 16; i++) {
        f32x4 v = *(const f32x4*)(base + i * 1024 + tid * 4);
        s += fabsf(v.x) + fabsf(v.y) + fabsf(v.z) + fabsf(v.w);
    }
#pragma unroll
    for (int off = 1; off < 64; off <<= 1) s += __shfl_xor(s, off);
    __shared__ float red[4];
    if ((tid & 63) == 0) red[tid >> 6] = s;
    __syncthreads();
    if (tid == 0) {
        double t = (double)red[0] + (double)red[1] + (double)red[2] + (double)red[3];
        atomicAdd(&wsum[w], t);
    }
}

// ---------------- ternary weight quantization ----------------
__global__ __launch_bounds__(256) void k_wquant(const float* __restrict__ w0, const float* __restrict__ w1,
                                                const float* __restrict__ w2, const float* __restrict__ w3,
                                                const double* __restrict__ wsum,
                                                __bf16* __restrict__ wq, float* __restrict__ wm) {
    int w = blockIdx.y;
    const float* W = (w == 0) ? w0 : (w == 1) ? w1 : (w == 2) ? w2 : w3;
    float mean = (float)(wsum[w] * (1.0 / 1048576.0));
    float ms = fmaxf(mean, EPSV);           // clip(mean, EPS)
    float scale = 1.0f / ms;
    int pos = blockIdx.x * 1024 + threadIdx.x * 4;
    f32x4 v = *(const f32x4*)(W + pos);
    float q0 = fminf(fmaxf(rintf(v.x * scale), -1.f), 1.f);
    float q1 = fminf(fmaxf(rintf(v.y * scale), -1.f), 1.f);
    float q2 = fminf(fmaxf(rintf(v.z * scale), -1.f), 1.f);
    float q3 = fminf(fmaxf(rintf(v.w * scale), -1.f), 1.f);
    unsigned int b0 = __builtin_bit_cast(unsigned short, (__bf16)q0);
    unsigned int b1 = __builtin_bit_cast(unsigned short, (__bf16)q1);
    unsigned int b2 = __builtin_bit_cast(unsigned short, (__bf16)q2);
    unsigned int b3 = __builtin_bit_cast(unsigned short, (__bf16)q3);
    uint2 p; p.x = b0 | (b1 << 16); p.y = b2 | (b3 << 16);
    *(uint2*)(wq + (size_t)w * 1048576 + pos) = p;
    if (blockIdx.x == 0 && threadIdx.x == 0) wm[w] = ms;   // weight multiplier = clip(mean|W|,EPS)
}

// ---------------- per-token int8 absmax act quant (stores integer values as bf16) ----------------
__global__ __launch_bounds__(256) void k_actq(const float* __restrict__ in, __bf16* __restrict__ outq,
                                              float* __restrict__ rs) {
    int t = blockIdx.x, tid = threadIdx.x;
    const float* row = in + (size_t)t * 1024;
    f32x4 v = *(const f32x4*)(row + tid * 4);
    float am = fmaxf(fmaxf(fabsf(v.x), fabsf(v.y)), fmaxf(fabsf(v.z), fabsf(v.w)));
#pragma unroll
    for (int off = 1; off < 64; off <<= 1) am = fmaxf(am, __shfl_xor(am, off));
    __shared__ float red[4];
    if ((tid & 63) == 0) red[tid >> 6] = am;
    __syncthreads();
    am = fmaxf(fmaxf(red[0], red[1]), fmaxf(red[2], red[3]));
    am = fmaxf(am, EPSV);                    // clip(absmax, EPS)
    float scale = 127.0f / am;
    float q0 = fminf(fmaxf(rintf(v.x * scale), -128.f), 127.f);
    float q1 = fminf(fmaxf(rintf(v.y * scale), -128.f), 127.f);
    float q2 = fminf(fmaxf(rintf(v.z * scale), -128.f), 127.f);
    float q3 = fminf(fmaxf(rintf(v.w * scale), -128.f), 127.f);
    unsigned int b0 = __builtin_bit_cast(unsigned short, (__bf16)q0);
    unsigned int b1 = __builtin_bit_cast(unsigned short, (__bf16)q1);
    unsigned int b2 = __builtin_bit_cast(unsigned short, (__bf16)q2);
    unsigned int b3 = __builtin_bit_cast(unsigned short, (__bf16)q3);
    uint2 p; p.x = b0 | (b1 << 16); p.y = b2 | (b3 << 16);
    *(uint2*)(outq + (size_t)t * 1024 + tid * 4) = p;
    if (tid == 0) rs[t] = am / 127.0f;       // 1/scale
}

// ---------------- GEMM: out[m][n] = sum_k X[m][k] * W[n][k], scaled by rs[m]*wm ----------------
// MODE 0: write bf16 into (b,h,s,hd) layout for q/k/v (z = blockIdx.z picks weight/output)
// MODE 1: write fp32 into d_out (T x 1024)
template <int MODE>
__global__ __launch_bounds__(256) void k_gemm(const __bf16* __restrict__ X, const __bf16* __restrict__ Wb,
                                              const float* __restrict__ rs, const float* __restrict__ wm,
                                              __bf16* __restrict__ o0, __bf16* __restrict__ o1,
                                              __bf16* __restrict__ o2, float* __restrict__ outf) {
    __shared__ __attribute__((aligned(16))) __bf16 As[128 * 32];
    __shared__ __attribute__((aligned(16))) __bf16 Bs[128 * 32];
    int tid = threadIdx.x;
    int wave = tid >> 6, lane = tid & 63, g = lane >> 4, l = lane & 15;
    int m0 = blockIdx.x * 128, n0 = blockIdx.y * 128;
    int z = blockIdx.z;
    const __bf16* W = Wb + (size_t)z * 1048576;
    float wmv = wm[z];
    f32x4 acc[4][4] = {};
    int srow = tid >> 1, scol = (tid & 1) * 16;
    const __bf16* Ag = X + (size_t)(m0 + srow) * 1024 + scol;
    const __bf16* Bg = W + (size_t)(n0 + srow) * 1024 + scol;
    int wrow = (wave >> 1) * 64, wcol = (wave & 1) * 64;
    for (int k0 = 0; k0 < 1024; k0 += 32) {
        u32x4 a0 = *(const u32x4*)(Ag + k0);
        u32x4 a1 = *(const u32x4*)(Ag + k0 + 8);
        u32x4 b0 = *(const u32x4*)(Bg + k0);
        u32x4 b1 = *(const u32x4*)(Bg + k0 + 8);
        __syncthreads();
        *(u32x4*)&As[srow * 32 + scol]     = a0;
        *(u32x4*)&As[srow * 32 + scol + 8] = a1;
        *(u32x4*)&Bs[srow * 32 + scol]     = b0;
        *(u32x4*)&Bs[srow * 32 + scol + 8] = b1;
        __syncthreads();
        bf16x8 af[4], bfr[4];
#pragma unroll
        for (int i = 0; i < 4; i++) af[i]  = *(const bf16x8*)&As[(wrow + i * 16 + l) * 32 + 8 * g];
#pragma unroll
        for (int i = 0; i < 4; i++) bfr[i] = *(const bf16x8*)&Bs[(wcol + i * 16 + l) * 32 + 8 * g];
#pragma unroll
        for (int mi = 0; mi < 4; mi++)
#pragma unroll
            for (int ni = 0; ni < 4; ni++)
                acc[mi][ni] = mfma16(af[mi], bfr[ni], acc[mi][ni]);
    }
    // epilogue: D layout row = 4*(lane>>4)+reg, col = lane&15 (guide-verified)
#pragma unroll
    for (int mi = 0; mi < 4; mi++) {
        int mbase = m0 + wrow + mi * 16 + 4 * g;
        f32x4 rv = {rs[mbase], rs[mbase + 1], rs[mbase + 2], rs[mbase + 3]};
#pragma unroll
        for (int ni = 0; ni < 4; ni++) {
            int n = n0 + wcol + ni * 16 + l;
#pragma unroll
            for (int r = 0; r < 4; r++) {
                float v = acc[mi][ni][r] * (rv[r] * wmv);
                if constexpr (MODE == 0) {
                    int m = mbase + r;
                    int b = m >> 11, s2 = m & 2047;
                    int h = n >> 6, hd = n & 63;
                    __bf16* dst = (z == 0) ? o0 : (z == 1) ? o1 : o2;
                    dst[(((size_t)(b * 16 + h)) * 2048 + s2) * 64 + hd] = (__bf16)v;
                } else {
                    outf[(size_t)(mbase + r) * 1024 + n] = v;
                }
            }
        }
    }
}

// ---------------- V transpose: vb[bh][s][hd] -> vt[bh][hd][s] ----------------
__global__ __launch_bounds__(256) void k_vtrans(const __bf16* __restrict__ vb, __bf16* __restrict__ vt) {
    __shared__ __attribute__((aligned(16))) __bf16 L[64 * 64];
    int tid = threadIdx.x;
    int s0 = blockIdx.x * 64, bh = blockIdx.y;
    int row = tid >> 2, cb = tid & 3;
    const __bf16* src = vb + ((size_t)bh * 2048 + s0 + row) * 64 + cb * 16;
    u32x4 v0 = *(const u32x4*)src;
    u32x4 v1 = *(const u32x4*)(src + 8);
    int sw = (row & 7) << 4;
    *(u32x4*)((char*)L + row * 128 + ((cb * 32) ^ sw))      = v0;
    *(u32x4*)((char*)L + row * 128 + ((cb * 32 + 16) ^ sw)) = v1;
    __syncthreads();
    int hd = tid >> 2, sb = tid & 3;
    union { unsigned short s[16]; u32x4 v[2]; } pk;
#pragma unroll
    for (int j = 0; j < 16; j++) {
        int r2 = sb * 16 + j;
        pk.s[j] = *(const unsigned short*)((const char*)L + r2 * 128 + ((2 * hd) ^ ((r2 & 7) << 4)));
    }
    __bf16* dst = vt + ((size_t)bh * 64 + hd) * 2048 + s0 + sb * 16;
    *(u32x4*)dst = pk.v[0];
    *(u32x4*)(dst + 8) = pk.v[1];
}

// ---------------- causal flash attention: q/k [bh][s][hd] bf16, vt [bh][hd][s] bf16 -> attn (B,S,D) fp32 ----------------
__global__ __launch_bounds__(256) void k_attn(const __bf16* __restrict__ qb, const __bf16* __restrict__ kb,
                                              const __bf16* __restrict__ vt, float* __restrict__ attn) {
    __shared__ __attribute__((aligned(16))) __bf16 Ks[64 * 64];   // [key][d], xor-swizzled
    __shared__ __attribute__((aligned(16))) __bf16 Vs[64 * 64];   // [hd][key], xor-swizzled
    __shared__ __attribute__((aligned(16))) __bf16 Ps[4][1024];   // per-wave [q16][key64], xor-swizzled
    int tid = threadIdx.x, wave = tid >> 6, lane = tid & 63, g = lane >> 4, l = lane & 15;
    int bh = blockIdx.y, qt0 = blockIdx.x * 64;
    size_t bhoff = (size_t)bh * 2048 * 64;
    int qrow = qt0 + wave * 16 + l;
    bf16x8 aq0 = *(const bf16x8*)(qb + bhoff + (size_t)qrow * 64 + 8 * g);
    bf16x8 aq1 = *(const bf16x8*)(qb + bhoff + (size_t)qrow * 64 + 32 + 8 * g);
    f32x4 o[4] = {};
    float mreg[4], lsum[4];
#pragma unroll
    for (int r = 0; r < 4; r++) { mreg[r] = -INFINITY; lsum[r] = 0.f; }
    int srow = tid >> 2, scb = tid & 3;
    const __bf16* Kg = kb + bhoff + (size_t)srow * 64 + scb * 16;
    const __bf16* Vg = vt + bhoff + (size_t)srow * 2048 + scb * 16;
    int swk = (srow & 7) << 4;
    char* Pw = (char*)&Ps[wave][0];
    int psw = (l & 7) << 4;
    int ntile = blockIdx.x + 1;
    for (int ti = 0; ti < ntile; ti++) {
        int t0 = ti * 64;
        u32x4 ka  = *(const u32x4*)(Kg + (size_t)t0 * 64);
        u32x4 kb4 = *(const u32x4*)(Kg + (size_t)t0 * 64 + 8);
        u32x4 va  = *(const u32x4*)(Vg + t0);
        u32x4 vb4 = *(const u32x4*)(Vg + t0 + 8);
        __syncthreads();
        *(u32x4*)((char*)Ks + srow * 128 + ((scb * 32) ^ swk))      = ka;
        *(u32x4*)((char*)Ks + srow * 128 + ((scb * 32 + 16) ^ swk)) = kb4;
        *(u32x4*)((char*)Vs + srow * 128 + ((scb * 32) ^ swk))      = va;
        *(u32x4*)((char*)Vs + srow * 128 + ((scb * 32 + 16) ^ swk)) = vb4;
        __syncthreads();
        // S = Q.K^T * 1/sqrt(64)
        f32x4 sv[4];
#pragma unroll
        for (int nb = 0; nb < 4; nb++) {
            int kr = nb * 16 + l;
            const char* kbase = (const char*)Ks + kr * 128;
            int sz = (kr & 7) << 4;
            bf16x8 bk0 = *(const bf16x8*)(kbase + ((16 * g) ^ sz));
            bf16x8 bk1 = *(const bf16x8*)(kbase + ((64 + 16 * g) ^ sz));
            f32x4 a = {};
            a = mfma16(aq0, bk0, a);
            a = mfma16(aq1, bk1, a);
            sv[nb] = a * 0.125f;
        }
        if (t0 == qt0) {   // diagonal tile: causal mask
#pragma unroll
            for (int nb = 0; nb < 4; nb++)
#pragma unroll
                for (int r = 0; r < 4; r++) {
                    int key = t0 + nb * 16 + l;
                    int q = qt0 + wave * 16 + 4 * g + r;
                    if (key > q) sv[nb][r] = -INFINITY;
                }
        }
        // online softmax (rows live on (g, reg); 16 lanes hold keys)
        float corr[4];
#pragma unroll
        for (int r = 0; r < 4; r++) {
            float v = fmaxf(fmaxf(sv[0][r], sv[1][r]), fmaxf(sv[2][r], sv[3][r]));
            v = fmaxf(v, __shfl_xor(v, 1));
            v = fmaxf(v, __shfl_xor(v, 2));
            v = fmaxf(v, __shfl_xor(v, 4));
            v = fmaxf(v, __shfl_xor(v, 8));
            float mnew = fmaxf(mreg[r], v);
            corr[r] = __expf(mreg[r] - mnew);
            mreg[r] = mnew;
        }
        float ps[4] = {0.f, 0.f, 0.f, 0.f};
#pragma unroll
        for (int nb = 0; nb < 4; nb++)
#pragma unroll
            for (int r = 0; r < 4; r++) {
                float p = __expf(sv[nb][r] - mreg[r]);
                sv[nb][r] = p;
                ps[r] += p;
            }
#pragma unroll
        for (int r = 0; r < 4; r++) {
            float s = ps[r];
            s += __shfl_xor(s, 1);
            s += __shfl_xor(s, 2);
            s += __shfl_xor(s, 4);
            s += __shfl_xor(s, 8);
            lsum[r] = lsum[r] * corr[r] + s;
#pragma unroll
            for (int hb = 0; hb < 4; hb++) o[hb][r] = o[hb][r] * corr[r];
        }
        // P -> LDS (bf16), then PV
#pragma unroll
        for (int nb = 0; nb < 4; nb++)
#pragma unroll
            for (int r = 0; r < 4; r++) {
                int prow = 4 * g + r;
                *(__bf16*)(Pw + prow * 128 + ((nb * 32 + 2 * l) ^ ((prow & 7) << 4))) = (__bf16)sv[nb][r];
            }
        bf16x8 pa0 = *(const bf16x8*)(Pw + l * 128 + ((16 * g) ^ psw));
        bf16x8 pa1 = *(const bf16x8*)(Pw + l * 128 + ((64 + 16 * g) ^ psw));
#pragma unroll
        for (int hb = 0; hb < 4; hb++) {
            int vr = hb * 16 + l;
            const char* vbase = (const char*)Vs + vr * 128;
            int sz = (vr & 7) << 4;
            bf16x8 v0 = *(const bf16x8*)(vbase + ((16 * g) ^ sz));
            bf16x8 v1 = *(const bf16x8*)(vbase + ((64 + 16 * g) ^ sz));
            o[hb] = mfma16(pa0, v0, o[hb]);
            o[hb] = mfma16(pa1, v1, o[hb]);
        }
    }
    // epilogue: write (B,S,D) fp32
    int b = bh >> 4, h = bh & 15;
#pragma unroll
    for (int r = 0; r < 4; r++) {
        float inv = 1.0f / lsum[r];
        int q = qt0 + wave * 16 + 4 * g + r;
        float* dst = attn + ((size_t)(b * 2048 + q)) * 1024 + h * 64 + l;
#pragma unroll
        for (int hb = 0; hb < 4; hb++) dst[hb * 16] = o[hb][r] * inv;
    }
}

extern "C" void kernel_launch(void* const* d_in, const int* in_sizes, int n_in,
                              void* d_out, int out_size, void* d_ws, size_t ws_size,
                              hipStream_t stream) {
    const float* x  = (const float*)d_in[0];
    // d_in[1] = mask: guaranteed causal tril, hardcoded in k_attn
    const float* Wq = (const float*)d_in[2];
    const float* Wk = (const float*)d_in[3];
    const float* Wv = (const float*)d_in[4];
    const float* Wo = (const float*)d_in[5];
    float* out = (float*)d_out;
    char* ws = (char*)d_ws;

    double* wsumd = (double*)(ws + 0);                       // 32 B
    float*  wmv   = (float*)(ws + 256);                      // 16 B
    __bf16* wqall = (__bf16*)(ws + 512);                     // 8 MB (4 x 1M bf16)
    __bf16* xq    = (__bf16*)(ws + 512 + 8388608);           // 8 MB
    float*  rsx   = (float*)(ws + 512 + 16777216);           // 16 KB
    float*  rso   = (float*)(ws + 512 + 16777216 + 16384);   // 16 KB
    char*   big   = ws + 512 + 16777216 + 32768;
    __bf16* qbuf  = (__bf16*)(big);                          // 8 MB
    __bf16* kbuf  = (__bf16*)(big + 8388608);                // 8 MB
    __bf16* vbuf  = (__bf16*)(big + 16777216);               // 8 MB
    __bf16* vtb   = (__bf16*)(big + 25165824);               // 8 MB
    float*  attn  = (float*)(big + 33554432);                // 16 MB
    __bf16* oq    = vbuf;                                    // alias: vbuf dead after k_vtrans

    hipMemsetAsync(ws, 0, 512, stream);
    k_wsum<<<dim3(256), 256, 0, stream>>>(Wq, Wk, Wv, Wo, wsumd);
    k_wquant<<<dim3(1024, 4), 256, 0, stream>>>(Wq, Wk, Wv, Wo, wsumd, wqall, wmv);
    k_actq<<<dim3(4096), 256, 0, stream>>>(x, xq, rsx);
    k_gemm<0><<<dim3(32, 8, 3), 256, 0, stream>>>(xq, wqall, rsx, wmv, qbuf, kbuf, vbuf, nullptr);
    k_vtrans<<<dim3(32, 32), 256, 0, stream>>>(vbuf, vtb);
    k_attn<<<dim3(32, 32), 256, 0, stream>>>(qbuf, kbuf, vtb, attn);
    k_actq<<<dim3(4096), 256, 0, stream>>>(attn, oq, rso);
    k_gemm<1><<<dim3(32, 8, 1), 256, 0, stream>>>(oq, wqall + 3 * 1048576, rso, wmv + 3,
                                                  nullptr, nullptr, nullptr, out);
}